// Round 6
// baseline (6154.750 us; speedup 1.0000x reference)
//
#include <hip/hip_runtime.h>
#include <cstdint>

#define BATCH 64
#define NODES 207
#define HID   64
#define NH    (NODES*HID)      // 13248
#define TOT   (BATCH*NH)       // 847872
#define NSTEPS 100
#define MT 28                  // m-rows per block tile
#define NT 8                   // 8 tiles/batch -> 512 blocks
#define ASTR 208               // padded A row stride (16B-aligned float4 reads)

// ---------------- threefry2x32 (JAX semantics) ----------------
__device__ __forceinline__ uint32_t rotl32(uint32_t v, int n) {
    return (v << n) | (v >> (32 - n));
}

__device__ __forceinline__ void threefry2x32(uint32_t k0, uint32_t k1,
                                             uint32_t& x0, uint32_t& x1) {
    uint32_t ks0 = k0, ks1 = k1, ks2 = k0 ^ k1 ^ 0x1BD11BDAu;
    x0 += ks0; x1 += ks1;
#define TF_ROUND(r) { x0 += x1; x1 = rotl32(x1, (r)); x1 ^= x0; }
    TF_ROUND(13) TF_ROUND(15) TF_ROUND(26) TF_ROUND(6)
    x0 += ks1; x1 += ks2 + 1u;
    TF_ROUND(17) TF_ROUND(29) TF_ROUND(16) TF_ROUND(24)
    x0 += ks2; x1 += ks0 + 2u;
    TF_ROUND(13) TF_ROUND(15) TF_ROUND(26) TF_ROUND(6)
    x0 += ks0; x1 += ks1 + 3u;
    TF_ROUND(17) TF_ROUND(29) TF_ROUND(16) TF_ROUND(24)
    x0 += ks1; x1 += ks2 + 4u;
    TF_ROUND(13) TF_ROUND(15) TF_ROUND(26) TF_ROUND(6)
    x0 += ks2; x1 += ks0 + 5u;
#undef TF_ROUND
}

// ---------------- erfinv (XLA f32 path, Giles) ----------------
__device__ __forceinline__ float erfinv32(float x) {
    float w = -log1pf(-x * x);
    float p;
    if (w < 5.0f) {
        w = w - 2.5f;
        p =             2.81022636e-08f;
        p = fmaf(p, w,  3.43273939e-07f);
        p = fmaf(p, w, -3.5233877e-06f);
        p = fmaf(p, w, -4.39150654e-06f);
        p = fmaf(p, w,  0.00021858087f);
        p = fmaf(p, w, -0.00125372503f);
        p = fmaf(p, w, -0.00417768164f);
        p = fmaf(p, w,  0.246640727f);
        p = fmaf(p, w,  1.50140941f);
    } else {
        w = sqrtf(w) - 3.0f;
        p =            -0.000200214257f;
        p = fmaf(p, w,  0.000100950558f);
        p = fmaf(p, w,  0.00134934322f);
        p = fmaf(p, w, -0.00367342844f);
        p = fmaf(p, w,  0.00573950773f);
        p = fmaf(p, w, -0.0076224613f);
        p = fmaf(p, w,  0.00943887047f);
        p = fmaf(p, w,  1.00167406f);
        p = fmaf(p, w,  2.83297682f);
    }
    return p * x;
}

// bits -> N(0,1) matching jax.random.normal f32 path
__device__ __forceinline__ float bits_to_normal(uint32_t bits) {
    uint32_t fb = (bits >> 9) | 0x3f800000u;
    float f = __uint_as_float(fb) - 1.0f;   // [0,1)
    const float lo = -0.99999994f;          // nextafter(-1,0)
    float u = f * 2.0f + lo;                // (maxval-minval) rounds to 2.0f
    u = fmaxf(lo, u);
    return 1.41421356237f * erfinv32(u);    // sqrt(2) f32
}

// ---------------- kernels ----------------

// y <- x copy; zero the per-batch barrier counters (re-zeroed every launch,
// so graph replays are safe).
__global__ void k_init(const float* __restrict__ x, float* __restrict__ y,
                       uint32_t* __restrict__ bar) {
    int tid = blockIdx.x * blockDim.x + threadIdx.x;
    int n4 = TOT / 4;
    int stride = gridDim.x * blockDim.x;
    for (int i = tid; i < n4; i += stride) {
        ((float4*)y)[i] = ((const float4*)x)[i];
    }
    if (tid < 1024) bar[tid] = 0u;
}

// Persistent fused Euler-Maruyama integrator: ONE launch runs all 100 steps.
//
// BLOCK->BATCH MAPPING IS THE CRITICAL PERF DECISION (r5 lesson):
//   b = bid & 63, t8 = bid >> 6  ->  a batch's 8 blocks are bids b, b+64, ...
//   With round-robin XCD dispatch (8 XCDs, 64 == 0 mod 8) all 8 land on ONE
//   XCD: y[b] stays in that XCD's L2 (848 KB/XCD working set vs 4 MB L2) and
//   the per-batch barrier is XCD-local. r5 used contiguous groups (bid>>3) ->
//   each batch spread over all 8 XCDs -> 6.8 MB/XCD -> L2 thrash, 12 MB/step
//   HBM fetch, 2.2x slower. Do not "simplify" this mapping.
//
// Deadlock safety: mapping-independent — grid=512 blocks = exactly 2/CU
// (LDS 31.7 KB, VGPR ~52), all blocks always co-resident.
//
// SPILL HISTORY — do not reintroduce:
//  * (512,4) -> VGPR cap 64 -> 500 MB/step scratch (r2).
//  * (512,2) + FULL unroll -> cap 128 still spilled (r3).
//  * (512,2) + unroll-2: live set fits, no scratch traffic (r4/r5 verified).
__global__ __launch_bounds__(512, 2) void k_persist(const float* __restrict__ A,
                                                    float* y0g,
                                                    float* y1g,
                                                    const float* __restrict__ Wt,
                                                    const float* __restrict__ bt,
                                                    const float* __restrict__ Wd,
                                                    const float* __restrict__ bd,
                                                    uint32_t* bar) {
    __shared__ __align__(16) float Alds[MT * ASTR];   // 23.3 KB
    __shared__ __align__(16) float AYs[MT * HID];     // 7.2 KB
    __shared__ uint32_t Klds[2 * NSTEPS];             // 0.8 KB -> 31.3 KB total
    int bid = blockIdx.x;
    int b   = bid & 63;                   // batch: every 64th block -> same XCD
    int t8  = bid >> 6;                   // tile 0..7
    int m0  = t8 * MT;                    // 0,28,...,196
    int h   = threadIdx.x & 63;
    int r   = __builtin_amdgcn_readfirstlane((int)(threadIdx.x >> 6));  // wave 0..7

    // ---- stage A-tile once (zero-fill rows past NODES) ----
    for (int row = r; row < MT; row += 8) {
        int m = m0 + row;
        const float* src = A + (size_t)m * NODES;
        bool v = (m < NODES);
        for (int c = h; c < NODES; c += 64)
            Alds[row*ASTR + c] = v ? src[c] : 0.0f;
    }
    // ---- derive the 100 step keys once: key_s = threefry((0,42), (0,s)) ----
    if (threadIdx.x < NSTEPS) {
        uint32_t x0 = 0u, x1 = (uint32_t)threadIdx.x;
        threefry2x32(0u, 42u, x0, x1);
        Klds[2*threadIdx.x]   = x0;
        Klds[2*threadIdx.x+1] = x1;
    }
    __syncthreads();

    // row-local indices this wave computes (clamped; garbage rows never stored)
    int rl[4];
#pragma unroll
    for (int i = 0; i < 4; ++i) {
        int t = r + 8*i;
        rl[i] = (t < MT) ? t : (MT - 1);
    }

    // loop-invariant bias values
    float btv = bt[h], bdv = bd[h];

    float* cur = y0g;
    float* nxt = y1g;
    uint32_t* mybar = bar + b * 16;       // 64B-spaced counters, one per batch

#pragma unroll 1
    for (int s = 0; s < NSTEPS; ++s) {
        const float* yb = cur + (size_t)b * NH;

        // ---- AY phase: 4 rows/wave, A via broadcast b128, y via coalesced global ----
        float acc[4] = {0.f, 0.f, 0.f, 0.f};
#pragma unroll 2
        for (int n = 0; n < 204; n += 4) {
            float y0 = yb[(n+0)*HID + h];
            float y1 = yb[(n+1)*HID + h];
            float y2 = yb[(n+2)*HID + h];
            float y3 = yb[(n+3)*HID + h];
#pragma unroll
            for (int i = 0; i < 4; ++i) {
                float4 a4 = *(const float4*)&Alds[rl[i]*ASTR + n];
                acc[i] = fmaf(a4.x, y0, acc[i]);      // n-order preserved
                acc[i] = fmaf(a4.y, y1, acc[i]);
                acc[i] = fmaf(a4.z, y2, acc[i]);
                acc[i] = fmaf(a4.w, y3, acc[i]);
            }
        }
#pragma unroll 1
        for (int n = 204; n < NODES; ++n) {           // tail: 204..206
            float yv = yb[n*HID + h];
#pragma unroll
            for (int i = 0; i < 4; ++i)
                acc[i] = fmaf(Alds[rl[i]*ASTR + n], yv, acc[i]);
        }

        // park AY rows (writer wave == reader wave -> no barrier needed)
#pragma unroll
        for (int i = 0; i < 4; ++i) {
            int t = r + 8*i;
            if (t < MT) AYs[t*HID + h] = acc[i];
        }

        // ---- T/D phase: broadcast b128 AY reads, coalesced Wt/Wd (L1-hit) ----
        float accT[4] = {0.f, 0.f, 0.f, 0.f};
        float accD[4] = {0.f, 0.f, 0.f, 0.f};
#pragma unroll 2
        for (int k = 0; k < HID; k += 4) {
            float wt0 = Wt[(k+0)*HID + h], wt1 = Wt[(k+1)*HID + h];
            float wt2 = Wt[(k+2)*HID + h], wt3 = Wt[(k+3)*HID + h];
            float wd0 = Wd[(k+0)*HID + h], wd1 = Wd[(k+1)*HID + h];
            float wd2 = Wd[(k+2)*HID + h], wd3 = Wd[(k+3)*HID + h];
#pragma unroll
            for (int i = 0; i < 4; ++i) {
                float4 a4 = *(const float4*)&AYs[rl[i]*HID + k];
                accT[i] = fmaf(a4.x, wt0, accT[i]);   // k-order preserved
                accT[i] = fmaf(a4.y, wt1, accT[i]);
                accT[i] = fmaf(a4.z, wt2, accT[i]);
                accT[i] = fmaf(a4.w, wt3, accT[i]);
                accD[i] = fmaf(a4.x, wd0, accD[i]);
                accD[i] = fmaf(a4.y, wd1, accD[i]);
                accD[i] = fmaf(a4.z, wd2, accD[i]);
                accD[i] = fmaf(a4.w, wd3, accD[i]);
            }
        }

        // ---- noise + update ----
        uint32_t kk0 = Klds[2*s], kk1 = Klds[2*s+1];
#pragma unroll
        for (int i = 0; i < 4; ++i) {
            int t = r + 8*i;
            int m = m0 + t;
            if (t < MT && m < NODES) {                // wave-uniform guard
                float F = 0.1f * tanhf(accT[i] + btv);
                float G = 0.1f * tanhf(accD[i] + bdv);
                uint32_t j = (uint32_t)(((size_t)b*NODES + m)*HID + h);
                uint32_t x0 = 0u, x1 = j;
                threefry2x32(kk0, kk1, x0, x1);
                float nrm = bits_to_normal(x0 ^ x1);
                float dW  = 0.1f * nrm;               // sqrt(0.01f) == 0.1f in f32
                float yold = yb[(size_t)m*HID + h];
                nxt[(size_t)b*NH + (size_t)m*HID + h] = (yold + F * 0.01f) + G * dW;
            }
        }

        // ---- per-batch barrier (monotonic counter; XCD-local with this mapping) ----
        __syncthreads();                  // all waves' stores issued+drained
        if (threadIdx.x == 0) {
            __threadfence();              // y stores device-visible before arrive
            atomicAdd(mybar, 1u);
            uint32_t tgt = 8u * (uint32_t)(s + 1);
            while (__hip_atomic_load(mybar, __ATOMIC_ACQUIRE,
                                     __HIP_MEMORY_SCOPE_AGENT) < tgt) {
                __builtin_amdgcn_s_sleep(2);
            }
            __threadfence();              // discard stale local caches
        }
        __syncthreads();

        float* tmp = cur; cur = nxt; nxt = tmp;
    }
}

// out[row, col] = tanh(sum_k y[row,k]*Wo[k,col] + bo[col])
// 4 cols/lane: float4 Wo loads + float4 stores, 64 fma per VMEM load.
// y values wave-uniform -> scalar loads on the SALU pipe.
#define OR 16
__global__ __launch_bounds__(256) void k_out(const float* __restrict__ y,
                                             const float* __restrict__ Wo,
                                             const float* __restrict__ bo,
                                             float* __restrict__ out) {
    int r0   = blockIdx.x * OR;                   // 828 row-tiles
    int col0 = blockIdx.y * 1024 + threadIdx.x * 4;  // 4 col-tiles
    const float* yb = y + (size_t)r0 * HID;
    float4 acc[OR];
#pragma unroll
    for (int r = 0; r < OR; ++r) acc[r] = make_float4(0.f, 0.f, 0.f, 0.f);
#pragma unroll 4
    for (int k = 0; k < HID; ++k) {
        float4 wv = *(const float4*)&Wo[(size_t)k*4096 + col0];
#pragma unroll
        for (int r = 0; r < OR; ++r) {
            float yv = yb[r*HID + k];             // uniform -> s_load
            acc[r].x = fmaf(yv, wv.x, acc[r].x);  // k ascending per chain
            acc[r].y = fmaf(yv, wv.y, acc[r].y);
            acc[r].z = fmaf(yv, wv.z, acc[r].z);
            acc[r].w = fmaf(yv, wv.w, acc[r].w);
        }
    }
    float4 bb = *(const float4*)&bo[col0];
#pragma unroll
    for (int r = 0; r < OR; ++r) {
        float4 o;
        o.x = tanhf(acc[r].x + bb.x);
        o.y = tanhf(acc[r].y + bb.y);
        o.z = tanhf(acc[r].z + bb.z);
        o.w = tanhf(acc[r].w + bb.w);
        *(float4*)&out[(size_t)(r0 + r)*4096 + col0] = o;
    }
}

extern "C" void kernel_launch(void* const* d_in, const int* in_sizes, int n_in,
                              void* d_out, int out_size, void* d_ws, size_t ws_size,
                              hipStream_t stream) {
    const float* x  = (const float*)d_in[0];
    const float* A  = (const float*)d_in[1];
    const float* Wt = (const float*)d_in[2];
    const float* bt = (const float*)d_in[3];
    const float* Wd = (const float*)d_in[4];
    const float* bd = (const float*)d_in[5];
    const float* Wo = (const float*)d_in[6];
    const float* bo = (const float*)d_in[7];
    float* out = (float*)d_out;

    float* y0 = (float*)d_ws;                 // 3.39 MB
    float* y1 = y0 + TOT;                     // 3.39 MB (ping-pong)
    uint32_t* bar = (uint32_t*)(y1 + TOT);    // 4 KB per-batch barrier counters

    k_init<<<512, 256, 0, stream>>>(x, y0, bar);
    k_persist<<<512, 512, 0, stream>>>(A, y0, y1, Wt, bt, Wd, bd, bar);
    // NSTEPS even -> final state back in y0
    k_out<<<dim3(NH/OR, 4096/1024), 256, 0, stream>>>(y0, Wo, bo, out);
}

// Round 7
// 2669.066 us; speedup vs baseline: 2.3060x; 2.3060x over previous
//
#include <hip/hip_runtime.h>
#include <cstdint>

#define BATCH 64
#define NODES 207
#define HID   64
#define NH    (NODES*HID)      // 13248
#define TOT   (BATCH*NH)       // 847872
#define NSTEPS 100
#define MT 28                  // m-rows per block tile
#define NT 8                   // 8 tiles -> grid (64,8) = 512 blocks = 2/CU (r4-proven mapping)
#define APSTR 208              // padded A row stride (16B-aligned rows -> s_load_dwordx4)
#define YSTR 212               // Y_T row stride in dwords (53 quads, odd -> conflict-free)
#define YQ   53                // quads per Y_T row

// ---------------- threefry2x32 (JAX semantics) ----------------
__device__ __forceinline__ uint32_t rotl32(uint32_t v, int n) {
    return (v << n) | (v >> (32 - n));
}

__device__ __forceinline__ void threefry2x32(uint32_t k0, uint32_t k1,
                                             uint32_t& x0, uint32_t& x1) {
    uint32_t ks0 = k0, ks1 = k1, ks2 = k0 ^ k1 ^ 0x1BD11BDAu;
    x0 += ks0; x1 += ks1;
#define TF_ROUND(r) { x0 += x1; x1 = rotl32(x1, (r)); x1 ^= x0; }
    TF_ROUND(13) TF_ROUND(15) TF_ROUND(26) TF_ROUND(6)
    x0 += ks1; x1 += ks2 + 1u;
    TF_ROUND(17) TF_ROUND(29) TF_ROUND(16) TF_ROUND(24)
    x0 += ks2; x1 += ks0 + 2u;
    TF_ROUND(13) TF_ROUND(15) TF_ROUND(26) TF_ROUND(6)
    x0 += ks0; x1 += ks1 + 3u;
    TF_ROUND(17) TF_ROUND(29) TF_ROUND(16) TF_ROUND(24)
    x0 += ks1; x1 += ks2 + 4u;
    TF_ROUND(13) TF_ROUND(15) TF_ROUND(26) TF_ROUND(6)
    x0 += ks2; x1 += ks0 + 5u;
#undef TF_ROUND
}

// ---------------- erfinv (XLA f32 path, Giles) ----------------
__device__ __forceinline__ float erfinv32(float x) {
    float w = -log1pf(-x * x);
    float p;
    if (w < 5.0f) {
        w = w - 2.5f;
        p =             2.81022636e-08f;
        p = fmaf(p, w,  3.43273939e-07f);
        p = fmaf(p, w, -3.5233877e-06f);
        p = fmaf(p, w, -4.39150654e-06f);
        p = fmaf(p, w,  0.00021858087f);
        p = fmaf(p, w, -0.00125372503f);
        p = fmaf(p, w, -0.00417768164f);
        p = fmaf(p, w,  0.246640727f);
        p = fmaf(p, w,  1.50140941f);
    } else {
        w = sqrtf(w) - 3.0f;
        p =            -0.000200214257f;
        p = fmaf(p, w,  0.000100950558f);
        p = fmaf(p, w,  0.00134934322f);
        p = fmaf(p, w, -0.00367342844f);
        p = fmaf(p, w,  0.00573950773f);
        p = fmaf(p, w, -0.0076224613f);
        p = fmaf(p, w,  0.00943887047f);
        p = fmaf(p, w,  1.00167406f);
        p = fmaf(p, w,  2.83297682f);
    }
    return p * x;
}

// bits -> N(0,1) matching jax.random.normal f32 path
__device__ __forceinline__ float bits_to_normal(uint32_t bits) {
    uint32_t fb = (bits >> 9) | 0x3f800000u;
    float f = __uint_as_float(fb) - 1.0f;   // [0,1)
    const float lo = -0.99999994f;          // nextafter(-1,0)
    float u = f * 2.0f + lo;                // (maxval-minval) rounds to 2.0f
    u = fmaxf(lo, u);
    return 1.41421356237f * erfinv32(u);    // sqrt(2) f32
}

// ---------------- kernels ----------------

// y <- x copy; build A_pad[207][208] (16B-aligned rows, zero pad col);
// derive the 100 step keys.
__global__ void k_init(const float* __restrict__ x, const float* __restrict__ A,
                       float* __restrict__ y, float* __restrict__ A_pad,
                       uint32_t* __restrict__ keys) {
    int tid = blockIdx.x * blockDim.x + threadIdx.x;
    int stride = gridDim.x * blockDim.x;
    for (int i = tid; i < TOT/4; i += stride) {
        ((float4*)y)[i] = ((const float4*)x)[i];
    }
    for (int i = tid; i < NODES*APSTR; i += stride) {
        int row = i / APSTR;
        int col = i - row*APSTR;
        A_pad[i] = (col < NODES) ? A[row*NODES + col] : 0.0f;
    }
    if (tid < NSTEPS) {
        uint32_t x0 = 0u, x1 = (uint32_t)tid;
        threefry2x32(0u, 42u, x0, x1);
        keys[2*tid]   = x0;
        keys[2*tid+1] = x1;
    }
}

// Fused Euler-Maruyama step, launched per step (persistent+barrier was 2.4x
// SLOWER — r5/r6: the per-step agent fences force L2 writeback; launch
// overhead is cheaper. Do not resurrect the in-kernel barrier.)
//
// Operand routing (r6 analysis: step was LDS+VMEM-ISSUE bound, VALUBusy 30%):
//  * y staged TRANSPOSED in LDS: Y_T[h][n], stride 212 dwords (53 quads, odd
//    quad stride -> b128 reads/writes conflict-free). AY inner loop: ONE
//    ds_read_b128 yields 4 n-values (was 4 VMEM loads + 4 LDS broadcasts).
//  * A read via wave-uniform s_load_dwordx4 from A_pad (16B-aligned rows)
//    -> scalar pipe, zero LDS/VMEM. This also frees the 23KB A-tile so the
//    54KB Y_T still allows 2 blocks/CU (60KB total LDS).
//
// SPILL HISTORY — do not reintroduce:
//  * __launch_bounds__(512,4) -> VGPR cap 64 -> 500 MB/step scratch (r2).
//  * __launch_bounds__(512,2) + full unroll -> cap 128 still spilled (r3).
//  * __launch_bounds__(512) + #pragma unroll 2: no spill (r4-r6 verified).
__global__ __launch_bounds__(512) void k_fused(const float* __restrict__ A_pad,
                                               const float* __restrict__ yin,
                                               float* __restrict__ yout,
                                               const float* __restrict__ Wt,
                                               const float* __restrict__ bt,
                                               const float* __restrict__ Wd,
                                               const float* __restrict__ bd,
                                               const uint32_t* __restrict__ keys,
                                               int s) {
    __shared__ __align__(16) float Ylds[64 * YSTR];   // 54.3 KB  (Y transposed)
    __shared__ __align__(16) float AYs[MT * HID];     // 7.2 KB -> 61.4 KB total
    int b  = blockIdx.x;                  // batch 0..63
    int m0 = blockIdx.y * MT;             // 0,28,...,196
    int h  = threadIdx.x & 63;
    int r  = __builtin_amdgcn_readfirstlane((int)(threadIdx.x >> 6));  // wave 0..7

    const float* yb = yin + (size_t)b * NH;

    // ---- stage Y_T: thread (h, g) gathers y[4g..4g+3][h] (4 coalesced loads)
    //      and writes one b128 quad at h*53+g (conflict-free: 5h mod 8 perm).
    {
        int g0 = (int)(threadIdx.x >> 6);
#pragma unroll
        for (int it = 0; it < 7; ++it) {
            int g = g0 + (it << 3);
            if (g < YQ) {
                int n = g << 2;
                float4 v;
                v.x = (n+0 < NODES) ? yb[(n+0)*HID + h] : 0.0f;
                v.y = (n+1 < NODES) ? yb[(n+1)*HID + h] : 0.0f;
                v.z = (n+2 < NODES) ? yb[(n+2)*HID + h] : 0.0f;
                v.w = (n+3 < NODES) ? yb[(n+3)*HID + h] : 0.0f;
                ((float4*)Ylds)[h*YQ + g] = v;
            }
        }
    }
    __syncthreads();

    // row-local indices (clamped; garbage rows never stored)
    int rl[4];
    const float* Ap[4];
#pragma unroll
    for (int i = 0; i < 4; ++i) {
        int t = r + 8*i;
        rl[i] = (t < MT) ? t : (MT - 1);
        int m = m0 + rl[i];
        int mc = (m < NODES) ? m : (NODES - 1);
        Ap[i] = A_pad + (size_t)mc * APSTR;       // wave-uniform -> s_load
    }

    // ---- AY phase: 1 ds_read_b128 (4 y's) + 4 s_load_dwordx4 (A) + 16 fma ----
    float acc[4] = {0.f, 0.f, 0.f, 0.f};
#pragma unroll 2
    for (int n = 0; n < 204; n += 4) {
        float4 y4 = ((const float4*)Ylds)[h*YQ + (n >> 2)];
#pragma unroll
        for (int i = 0; i < 4; ++i) {
            float4 a4 = *(const float4*)&Ap[i][n];
            acc[i] = fmaf(a4.x, y4.x, acc[i]);    // n-order preserved (bit-exact)
            acc[i] = fmaf(a4.y, y4.y, acc[i]);
            acc[i] = fmaf(a4.z, y4.z, acc[i]);
            acc[i] = fmaf(a4.w, y4.w, acc[i]);
        }
    }
#pragma unroll 1
    for (int n = 204; n < NODES; ++n) {           // tail: 204..206
        float yv = Ylds[h*YSTR + n];
#pragma unroll
        for (int i = 0; i < 4; ++i)
            acc[i] = fmaf(Ap[i][n], yv, acc[i]);
    }

    // park AY rows (writer wave == reader wave -> no barrier needed)
#pragma unroll
    for (int i = 0; i < 4; ++i) {
        int t = r + 8*i;
        if (t < MT) AYs[t*HID + h] = acc[i];
    }

    // ---- T/D phase: broadcast b128 AY reads, coalesced Wt/Wd (identical to r4) ----
    float accT[4] = {0.f, 0.f, 0.f, 0.f};
    float accD[4] = {0.f, 0.f, 0.f, 0.f};
#pragma unroll 2
    for (int k = 0; k < HID; k += 4) {
        float wt0 = Wt[(k+0)*HID + h], wt1 = Wt[(k+1)*HID + h];
        float wt2 = Wt[(k+2)*HID + h], wt3 = Wt[(k+3)*HID + h];
        float wd0 = Wd[(k+0)*HID + h], wd1 = Wd[(k+1)*HID + h];
        float wd2 = Wd[(k+2)*HID + h], wd3 = Wd[(k+3)*HID + h];
#pragma unroll
        for (int i = 0; i < 4; ++i) {
            float4 a4 = *(const float4*)&AYs[rl[i]*HID + k];
            accT[i] = fmaf(a4.x, wt0, accT[i]);   // k-order preserved (bit-exact)
            accT[i] = fmaf(a4.y, wt1, accT[i]);
            accT[i] = fmaf(a4.z, wt2, accT[i]);
            accT[i] = fmaf(a4.w, wt3, accT[i]);
            accD[i] = fmaf(a4.x, wd0, accD[i]);
            accD[i] = fmaf(a4.y, wd1, accD[i]);
            accD[i] = fmaf(a4.z, wd2, accD[i]);
            accD[i] = fmaf(a4.w, wd3, accD[i]);
        }
    }

    // ---- noise + update (yold from Y_T in LDS — no global re-read) ----
    uint32_t kk0 = keys[2*s], kk1 = keys[2*s+1];
    float btv = bt[h], bdv = bd[h];
#pragma unroll
    for (int i = 0; i < 4; ++i) {
        int t = r + 8*i;
        int m = m0 + t;
        if (t < MT && m < NODES) {                // wave-uniform guard
            float F = 0.1f * tanhf(accT[i] + btv);
            float G = 0.1f * tanhf(accD[i] + bdv);
            uint32_t j = (uint32_t)(((size_t)b*NODES + m)*HID + h);
            uint32_t x0 = 0u, x1 = j;
            threefry2x32(kk0, kk1, x0, x1);
            float nrm = bits_to_normal(x0 ^ x1);
            float dW  = 0.1f * nrm;               // sqrt(0.01f) == 0.1f in f32
            float yold = Ylds[h*YSTR + m];        // == y[m][h], staged this step
            yout[(size_t)b*NH + (size_t)m*HID + h] = (yold + F * 0.01f) + G * dW;
        }
    }
}

// out[row, col] = tanh(sum_k y[row,k]*Wo[k,col] + bo[col])
// 4 cols/lane: float4 Wo loads + float4 stores, 64 fma per VMEM load.
// y values wave-uniform -> scalar loads on the SALU pipe.
#define OR 16
__global__ __launch_bounds__(256) void k_out(const float* __restrict__ y,
                                             const float* __restrict__ Wo,
                                             const float* __restrict__ bo,
                                             float* __restrict__ out) {
    int r0   = blockIdx.x * OR;                   // 828 row-tiles
    int col0 = blockIdx.y * 1024 + threadIdx.x * 4;  // 4 col-tiles
    const float* yb = y + (size_t)r0 * HID;
    float4 acc[OR];
#pragma unroll
    for (int r = 0; r < OR; ++r) acc[r] = make_float4(0.f, 0.f, 0.f, 0.f);
#pragma unroll 4
    for (int k = 0; k < HID; ++k) {
        float4 wv = *(const float4*)&Wo[(size_t)k*4096 + col0];
#pragma unroll
        for (int r = 0; r < OR; ++r) {
            float yv = yb[r*HID + k];             // uniform -> s_load
            acc[r].x = fmaf(yv, wv.x, acc[r].x);  // k ascending per chain
            acc[r].y = fmaf(yv, wv.y, acc[r].y);
            acc[r].z = fmaf(yv, wv.z, acc[r].z);
            acc[r].w = fmaf(yv, wv.w, acc[r].w);
        }
    }
    float4 bb = *(const float4*)&bo[col0];
#pragma unroll
    for (int r = 0; r < OR; ++r) {
        float4 o;
        o.x = tanhf(acc[r].x + bb.x);
        o.y = tanhf(acc[r].y + bb.y);
        o.z = tanhf(acc[r].z + bb.z);
        o.w = tanhf(acc[r].w + bb.w);
        *(float4*)&out[(size_t)(r0 + r)*4096 + col0] = o;
    }
}

extern "C" void kernel_launch(void* const* d_in, const int* in_sizes, int n_in,
                              void* d_out, int out_size, void* d_ws, size_t ws_size,
                              hipStream_t stream) {
    const float* x  = (const float*)d_in[0];
    const float* A  = (const float*)d_in[1];
    const float* Wt = (const float*)d_in[2];
    const float* bt = (const float*)d_in[3];
    const float* Wd = (const float*)d_in[4];
    const float* bd = (const float*)d_in[5];
    const float* Wo = (const float*)d_in[6];
    const float* bo = (const float*)d_in[7];
    float* out = (float*)d_out;

    float* y0 = (float*)d_ws;                   // 3.39 MB
    float* y1 = y0 + TOT;                       // 3.39 MB (ping-pong)
    uint32_t* keys = (uint32_t*)(y1 + TOT);     // 800 B (+pad)
    float* A_pad = (float*)(keys + 256);        // 207*208*4 = 172 KB

    k_init<<<512, 256, 0, stream>>>(x, A, y0, A_pad, keys);
    float* cur = y0;
    float* nxt = y1;
    for (int s = 0; s < NSTEPS; ++s) {
        k_fused<<<dim3(BATCH, NT), 512, 0, stream>>>(A_pad, cur, nxt, Wt, bt, Wd, bd, keys, s);
        float* t = cur; cur = nxt; nxt = t;
    }
    k_out<<<dim3(NH/OR, 4096/1024), 256, 0, stream>>>(cur, Wo, bo, out);
}